// Round 1
// baseline (450.639 us; speedup 1.0000x reference)
//
#include <hip/hip_runtime.h>
#include <hip/hip_bf16.h>
#include <stdint.h>

#define NN 4096

typedef __attribute__((ext_vector_type(8))) short short8;
typedef __attribute__((ext_vector_type(4))) float floatx4;

#define AS1C const __attribute__((address_space(1))) void*
#define AS3  __attribute__((address_space(3))) void*

// ---------------------------------------------------------------------------
// K1: build sorted neighbor lists (ascending col index) + true degree.
// One wave per row; ballot-compaction preserves index order.
// ---------------------------------------------------------------------------
__global__ __launch_bounds__(256) void nbr_k(const float* __restrict__ adj,
                                             int* __restrict__ nbr,
                                             int* __restrict__ deg) {
    int tid = threadIdx.x;
    int wv = tid >> 6, ln = tid & 63;
    int v = blockIdx.x * 4 + wv;
    size_t rb = (size_t)v * NN;
    int total = 0;
    for (int base = 0; base < NN; base += 64) {
        float val = adj[rb + base + ln];
        bool p = val > 0.5f;
        unsigned long long m = __ballot(p);
        if (p) {
            int pos = total + __popcll(m & ((1ull << ln) - 1ull));
            if (pos < 64) nbr[v * 64 + pos] = base + ln;
        }
        total += __popcll(m);
    }
    if (ln == 0) deg[v] = total;
}

// ---------------------------------------------------------------------------
// K2: cr_feat (cols 0..3) + degree_feat (cols 12..14). One wave per node.
// Closed neighborhood = sorted {v} ∪ N(v)  (matches jax top_k stable order).
// 64-bit bitmask per member row; E/W via common-neighbor popcounts,
// T = trace(S^3)/6.
// ---------------------------------------------------------------------------
__global__ __launch_bounds__(256) void crfeat_k(const float* __restrict__ adj,
                                                const int* __restrict__ nbr,
                                                const int* __restrict__ deg,
                                                float* __restrict__ feats) {
    __shared__ unsigned long long rows[4][64];
    __shared__ int mems[4][64];
    int tid = threadIdx.x;
    int wv = tid >> 6, ln = tid & 63;
    int v = blockIdx.x * 4 + wv;

    int dv = deg[v];
    int degL = min(dv, 64);
    int c = min(dv + 1, 64);

    // position of v within sorted member list = #neighbors with index < v
    int isless = (ln < degL && nbr[v * 64 + ln] < v) ? 1 : 0;
    int pos = isless;
    #pragma unroll
    for (int off = 32; off; off >>= 1) pos += __shfl_xor(pos, off, 64);

    int mem = 0;
    if (ln < c) {
        if (ln < pos)       mem = nbr[v * 64 + ln];
        else if (ln == pos) mem = v;
        else                mem = nbr[v * 64 + ln - 1];
    }
    mems[wv][ln] = mem;
    __syncthreads();

    unsigned long long mask = 0;
    if (ln < c) {
        if (ln == pos) {
            mask = (c >= 64 ? ~0ull : ((1ull << c) - 1ull)) ^ (1ull << pos);
        } else {
            size_t rowbase = (size_t)mem * NN;
            for (int j = 0; j < c; j++) {
                if (j == ln) continue;
                int mj = mems[wv][j];
                if (adj[rowbase + mj] > 0.5f) mask |= 1ull << j;
            }
        }
    }
    rows[wv][ln] = mask;
    __syncthreads();

    int tpart = 0;
    float epart = 0.f, wpart = 0.f;
    if (ln < c) {
        unsigned long long mm = mask;
        while (mm) {
            int j = __ffsll(mm) - 1;
            mm &= mm - 1;
            tpart += __popcll(mask & rows[wv][j]);
        }
        if (ln != pos) {
            int cn = __popcll(rows[wv][pos] & mask);
            float D = (float)cn + 1.0f;
            epart = D;
            wpart = D * (D - 1.0f) * 0.5f;
        }
    }
    float es = epart, wsum = wpart;
    int ts = tpart;
    #pragma unroll
    for (int off = 32; off; off >>= 1) {
        es += __shfl_xor(es, off, 64);
        wsum += __shfl_xor(wsum, off, 64);
        ts += __shfl_xor(ts, off, 64);
    }

    if (ln == 0) {
        float degf = (float)dv;
        float k = degf + 1.0f;
        float E = 0.5f * (es + degf);
        float W = wsum + degf * (degf - 1.0f) * 0.5f;
        float T = (float)ts / 6.0f;
        float f3 = T;
        float f2 = W - 3.0f * T;
        float f1 = E * (k - 2.0f) - 2.0f * f2 - 3.0f * f3;
        float tot = k * (k - 1.0f) * (k - 2.0f) / 6.0f;
        float f0 = tot - f1 - f2 - f3;
        if (k < 3.0f) { f0 = f1 = f2 = f3 = 0.f; }
        float s = f0 + f1 + f2 + f3 + 1e-10f;
        feats[v * 16 + 0] = f0 / s;
        feats[v * 16 + 1] = f1 / s;
        feats[v * 16 + 2] = f2 / s;
        feats[v * 16 + 3] = f3 / s;
        feats[v * 16 + 12] = degf;
        feats[v * 16 + 13] = degf * degf;
        feats[v * 16 + 14] = degf;   // diag(A^2) = deg for symmetric 0/1
    }
}

// ---------------------------------------------------------------------------
// K3: a2 = adj @ adj, built sparsely via LDS scatter, stored dense bf16 bits.
// One block per row. Values are small ints (<256) -> bf16-exact (truncate
// float bits; mantissa already exact).
// ---------------------------------------------------------------------------
__global__ __launch_bounds__(256) void a2_k(const int* __restrict__ nbr,
                                            const int* __restrict__ deg,
                                            unsigned short* __restrict__ a2) {
    __shared__ unsigned int acc[NN];
    int tid = threadIdx.x;
    int v = blockIdx.x;
    for (int j = tid; j < NN; j += 256) acc[j] = 0u;
    __syncthreads();
    int dv = min(deg[v], 64);
    for (int p = tid; p < dv * 64; p += 256) {
        int u = nbr[v * 64 + (p >> 6)];
        int wi = p & 63;
        if (wi < min(deg[u], 64)) atomicAdd(&acc[nbr[u * 64 + wi]], 1u);
    }
    __syncthreads();
    int j0 = tid * 16;
    unsigned short h[16];
    #pragma unroll
    for (int m = 0; m < 16; m++) {
        float f = (float)acc[j0 + m];
        h[m] = (unsigned short)(__float_as_uint(f) >> 16);
    }
    uint4* dst = (uint4*)(a2 + (size_t)v * NN + j0);
    dst[0] = *(uint4*)(h);
    dst[1] = *(uint4*)(h + 8);
}

// ---------------------------------------------------------------------------
// K4: a4 = a2 @ a2 (bf16 in, fp32 out) — m97-style MFMA GEMM.
// 128x128 tile / block, BK=32, 4 waves each 64x64 (4x4 frags of 16x16x32),
// staging via global_load_lds width 16. a2 symmetric -> B^T rows = a2 rows.
// ---------------------------------------------------------------------------
__global__ __launch_bounds__(256) void gemm_k(const unsigned short* __restrict__ A,
                                              float* __restrict__ C) {
    __shared__ unsigned short As[128 * 32];
    __shared__ unsigned short Bs[128 * 32];
    int tid = threadIdx.x;
    int wv = tid >> 6, ln = tid & 63;
    int bx = blockIdx.x & 31, by = blockIdx.x >> 5;
    int rowbase = by * 128, colbase = bx * 128;
    int wr = (wv >> 1) * 64, wc = (wv & 1) * 64;

    floatx4 acc[4][4];
    #pragma unroll
    for (int mi = 0; mi < 4; mi++)
        #pragma unroll
        for (int ni = 0; ni < 4; ni++)
            acc[mi][ni] = (floatx4){0.f, 0.f, 0.f, 0.f};

    int srow = tid >> 2;          // 0..63
    int scol = (tid & 3) << 3;    // 0,8,16,24
    const unsigned short* gA0 = A + (size_t)(rowbase + srow) * NN + scol;
    const unsigned short* gA1 = gA0 + (size_t)64 * NN;
    const unsigned short* gB0 = A + (size_t)(colbase + srow) * NN + scol;
    const unsigned short* gB1 = gB0 + (size_t)64 * NN;
    unsigned short* lA0 = As + wv * 512;          // wave-uniform bases
    unsigned short* lA1 = As + 2048 + wv * 512;
    unsigned short* lB0 = Bs + wv * 512;
    unsigned short* lB1 = Bs + 2048 + wv * 512;

    const unsigned short* fA = As + ((wr + (ln & 15)) * 32 + ((ln >> 4) << 3));
    const unsigned short* fB = Bs + ((wc + (ln & 15)) * 32 + ((ln >> 4) << 3));

    for (int kt = 0; kt < NN; kt += 32) {
        __syncthreads();
        __builtin_amdgcn_global_load_lds((AS1C)(gA0 + kt), (AS3)lA0, 16, 0, 0);
        __builtin_amdgcn_global_load_lds((AS1C)(gA1 + kt), (AS3)lA1, 16, 0, 0);
        __builtin_amdgcn_global_load_lds((AS1C)(gB0 + kt), (AS3)lB0, 16, 0, 0);
        __builtin_amdgcn_global_load_lds((AS1C)(gB1 + kt), (AS3)lB1, 16, 0, 0);
        __syncthreads();
        short8 a[4], b[4];
        #pragma unroll
        for (int mi = 0; mi < 4; mi++) a[mi] = *(const short8*)(fA + mi * 512);
        #pragma unroll
        for (int ni = 0; ni < 4; ni++) b[ni] = *(const short8*)(fB + ni * 512);
        #pragma unroll
        for (int mi = 0; mi < 4; mi++)
            #pragma unroll
            for (int ni = 0; ni < 4; ni++)
                acc[mi][ni] = __builtin_amdgcn_mfma_f32_16x16x32_bf16(
                    a[mi], b[ni], acc[mi][ni], 0, 0, 0);
    }

    // C/D layout: col = lane&15, row = (lane>>4)*4 + reg
    #pragma unroll
    for (int mi = 0; mi < 4; mi++) {
        #pragma unroll
        for (int ni = 0; ni < 4; ni++) {
            #pragma unroll
            for (int r = 0; r < 4; r++) {
                int row = rowbase + wr + mi * 16 + ((ln >> 4) << 2) + r;
                int col = colbase + wc + ni * 16 + (ln & 15);
                C[(size_t)row * NN + col] = acc[mi][ni][r];
            }
        }
    }
}

// ---------------------------------------------------------------------------
// K5: top-8 per row of a4 -> feats cols 4..11 (descending, matches top_k).
// One wave per row; per-lane sorted top-8 then 8 rounds of wave max-extract.
// ---------------------------------------------------------------------------
__global__ __launch_bounds__(256) void top8_k(const float* __restrict__ a4,
                                              float* __restrict__ feats) {
    int tid = threadIdx.x;
    int wv = tid >> 6, ln = tid & 63;
    int v = blockIdx.x * 4 + wv;
    const float* rowp = a4 + (size_t)v * NN;
    float best[8];
    #pragma unroll
    for (int i = 0; i < 8; i++) best[i] = -1.f;
    for (int j = ln; j < NN; j += 64) {
        float val = rowp[j];
        if (val > best[7]) {
            best[7] = val;
            #pragma unroll
            for (int s = 7; s > 0; s--) {
                if (best[s] > best[s - 1]) {
                    float tmp = best[s - 1]; best[s - 1] = best[s]; best[s] = tmp;
                } else break;
            }
        }
    }
    for (int r = 0; r < 8; r++) {
        float cand = best[0];
        float m = cand;
        #pragma unroll
        for (int off = 32; off; off >>= 1) m = fmaxf(m, __shfl_xor(m, off, 64));
        unsigned long long b = __ballot(cand == m);
        int src = __ffsll(b) - 1;
        if (ln == src) {
            #pragma unroll
            for (int s = 0; s < 7; s++) best[s] = best[s + 1];
            best[7] = -1.f;
        }
        if (ln == 0) feats[v * 16 + 4 + r] = m;
    }
}

// ---------------------------------------------------------------------------
// K6: x = feats @ e_w + e_b   (4096x15 · 15x64)
// ---------------------------------------------------------------------------
__global__ __launch_bounds__(64) void embed_k(const float* __restrict__ feats,
                                              const float* __restrict__ e_w,
                                              const float* __restrict__ e_b,
                                              float* __restrict__ x) {
    int v = blockIdx.x, d = threadIdx.x;
    float s = e_b[d];
    #pragma unroll
    for (int j = 0; j < 15; j++) s += feats[v * 16 + j] * e_w[j * 64 + d];
    x[(size_t)v * 64 + d] = s;
}

// ---------------------------------------------------------------------------
// K7: one GNN layer: h = (1+eps)x + A x ; x' = relu(h W1 + b1) W2 + b2
// One wave per node; sparse aggregation over neighbor list.
// ---------------------------------------------------------------------------
__global__ __launch_bounds__(64) void layer_k(const float* __restrict__ xin,
                                              float* __restrict__ xout,
                                              const float* __restrict__ w1,
                                              const float* __restrict__ b1,
                                              const float* __restrict__ w2,
                                              const float* __restrict__ b2,
                                              const float* __restrict__ eps,
                                              const int* __restrict__ nbr,
                                              const int* __restrict__ deg,
                                              int li) {
    __shared__ float h[64], t[64];
    int v = blockIdx.x, d = threadIdx.x;
    float xv = xin[(size_t)v * 64 + d];
    float agg = 0.f;
    int dv = min(deg[v], 64);
    for (int j = 0; j < dv; j++) agg += xin[(size_t)nbr[v * 64 + j] * 64 + d];
    float hv = (1.0f + eps[li]) * xv + agg;
    h[d] = hv;
    __syncthreads();
    float s = b1[li * 64 + d];
    #pragma unroll 8
    for (int j = 0; j < 64; j++) s += h[j] * w1[li * 4096 + j * 64 + d];
    s = fmaxf(s, 0.f);
    t[d] = s;
    __syncthreads();
    float o = b2[li * 64 + d];
    #pragma unroll 8
    for (int j = 0; j < 64; j++) o += t[j] * w2[li * 4096 + j * 64 + d];
    xout[(size_t)v * 64 + d] = o;
}

// ---------------------------------------------------------------------------
// K8/K9: deterministic two-stage column sum: out = x.sum(0)
// ---------------------------------------------------------------------------
__global__ __launch_bounds__(256) void sum_k(const float* __restrict__ x,
                                             float* __restrict__ partial) {
    __shared__ float p[256];
    int tid = threadIdx.x;
    int d = tid & 63, g = tid >> 6;
    float s = 0.f;
    for (int v = blockIdx.x * 4 + g; v < NN; v += 1024)
        s += x[(size_t)v * 64 + d];
    p[tid] = s;
    __syncthreads();
    if (tid < 64)
        partial[blockIdx.x * 64 + tid] = p[tid] + p[tid + 64] + p[tid + 128] + p[tid + 192];
}

__global__ __launch_bounds__(256) void final_k(const float* __restrict__ partial,
                                               float* __restrict__ out) {
    __shared__ float p[256];
    int tid = threadIdx.x;
    int d = tid & 63, g = tid >> 6;
    float s = 0.f;
    for (int b = g; b < 256; b += 4) s += partial[b * 64 + d];
    p[tid] = s;
    __syncthreads();
    if (tid < 64) out[tid] = p[tid] + p[tid + 64] + p[tid + 128] + p[tid + 192];
}

// ---------------------------------------------------------------------------
extern "C" void kernel_launch(void* const* d_in, const int* in_sizes, int n_in,
                              void* d_out, int out_size, void* d_ws, size_t ws_size,
                              hipStream_t stream) {
    const float* adj = (const float*)d_in[0];
    const float* e_w = (const float*)d_in[1];
    const float* e_b = (const float*)d_in[2];
    const float* w1  = (const float*)d_in[3];
    const float* b1  = (const float*)d_in[4];
    const float* w2  = (const float*)d_in[5];
    const float* b2  = (const float*)d_in[6];
    const float* eps = (const float*)d_in[7];
    float* out = (float*)d_out;

    char* ws = (char*)d_ws;
    // workspace carve-up (~104.2 MB total)
    float*          a4      = (float*)(ws);                       // 64 MB
    unsigned short* a2      = (unsigned short*)(ws + 67108864);   // 32 MB
    int*            nbr     = (int*)(ws + 100663296);             // 1 MB
    int*            deg     = (int*)(ws + 101711872);             // 16 KB
    float*          feats   = (float*)(ws + 101728256);           // 256 KB (4096x16, col 15 pad)
    float*          x0      = (float*)(ws + 101990400);           // 1 MB
    float*          x1      = (float*)(ws + 103038976);           // 1 MB
    float*          partial = (float*)(ws + 104087552);           // 64 KB

    nbr_k<<<1024, 256, 0, stream>>>(adj, nbr, deg);
    crfeat_k<<<1024, 256, 0, stream>>>(adj, nbr, deg, feats);
    a2_k<<<4096, 256, 0, stream>>>(nbr, deg, a2);
    gemm_k<<<1024, 256, 0, stream>>>(a2, a4);
    top8_k<<<1024, 256, 0, stream>>>(a4, feats);
    embed_k<<<4096, 64, 0, stream>>>(feats, e_w, e_b, x0);
    layer_k<<<4096, 64, 0, stream>>>(x0, x1, w1, b1, w2, b2, eps, nbr, deg, 0);
    layer_k<<<4096, 64, 0, stream>>>(x1, x0, w1, b1, w2, b2, eps, nbr, deg, 1);
    layer_k<<<4096, 64, 0, stream>>>(x0, x1, w1, b1, w2, b2, eps, nbr, deg, 2);
    sum_k<<<256, 256, 0, stream>>>(x1, partial);
    final_k<<<1, 256, 0, stream>>>(partial, out);
}